// Round 11
// baseline (143.192 us; speedup 1.0000x reference)
//
#include <hip/hip_runtime.h>

// MCA linear attention, fp32. B=8, C=64, H=W=160, P=8 heads, d=8, N=25600.
#define NPIX  25600
#define NB    8
#define NCH   100    // pixel chunks per batch
#define CPX   256    // pixels per chunk (64 lanes x 4 px)
#define EPSV  1e-6f

// workspace layout (float offsets)
#define WS_WKVT  0        // [8 h][64 c][16]  (8 wk rows, 8 wv rows, transposed)
#define WS_WQT   8192     // [8 h][64 c][8]
#define WS_BKV   12288    // [8 h][16]
#define WS_BQ    12416    // [8 h][8]
#define WS_PART  12480    // [64 bh][100 ch][72]  (contiguous 72 per chunk)
#define WS_G     473280   // [8 b][64 pm][64 o]
#define WS_KSE   506048   // [8 b][8 p][8 m]

__device__ __forceinline__ float softplus_(float x) {
  // hw v_exp/v_log path; for x>20, log(1+e^x)==x to fp32 precision
  return (x > 20.0f) ? x : __logf(1.0f + __expf(x));
}

// async global->LDS: each lane reads 16B at its own global addr; HW writes
// LDS at (uniform base) + lane*16 (guide m97/m104 semantics).
__device__ __forceinline__ void gload_lds16(const float* g, float* lds_base) {
  __builtin_amdgcn_global_load_lds((const unsigned int*)g, (unsigned int*)lds_base,
                                   16, 0, 0);
}

// DPP wave64 sum: row_shr 1/2/4/8 then row_bcast:15 (rows 1,3) and
// row_bcast:31 (rows 2,3). Full sum lands in lane 63. old=0 makes masked /
// invalid lanes contribute 0 regardless of bound_ctrl interpretation.
template <int CTRL, int RMASK>
__device__ __forceinline__ float dpp_add(float x) {
  int y = __builtin_amdgcn_update_dpp(0, __float_as_int(x), CTRL, RMASK, 0xf, false);
  return x + __int_as_float(y);
}
__device__ __forceinline__ float wave_sum63(float x) {
  x = dpp_add<0x111, 0xf>(x);   // row_shr:1
  x = dpp_add<0x112, 0xf>(x);   // row_shr:2
  x = dpp_add<0x114, 0xf>(x);   // row_shr:4
  x = dpp_add<0x118, 0xf>(x);   // row_shr:8
  x = dpp_add<0x142, 0xa>(x);   // row_bcast:15 -> rows 1,3
  x = dpp_add<0x143, 0xc>(x);   // row_bcast:31 -> rows 2,3
  return x;                     // lane 63 holds the wave total
}

// ---------------- kernel 0: pack weights/biases transposed ----------------
__global__ void k0_pack(const float* __restrict__ wq_high, const float* __restrict__ bq_high,
                        const float* __restrict__ wq_low,  const float* __restrict__ bq_low,
                        const float* __restrict__ wk, const float* __restrict__ bk,
                        const float* __restrict__ wv, const float* __restrict__ bv,
                        float* __restrict__ ws) {
  const int tid = threadIdx.x;
  for (int e = tid; e < 8192; e += 256) {        // wkvT[h][c][j]
    int j = e & 15, c = (e >> 4) & 63, h = e >> 10, m = j & 7;
    float v = (j < 8) ? wk[(h * 8 + m) * 64 + c] : wv[(h * 8 + m) * 64 + c];
    ws[WS_WKVT + e] = v;
  }
  for (int e = tid; e < 4096; e += 256) {        // wqT[h][c][m]
    int m = e & 7, c = (e >> 3) & 63, h = e >> 9;
    float v = (h < 4) ? wq_high[(h * 8 + m) * 64 + c]
                      : wq_low[((h - 4) * 8 + m) * 64 + c];
    ws[WS_WQT + e] = v;
  }
  for (int e = tid; e < 128; e += 256) {         // bkv[h][j]
    int j = e & 15, h = e >> 4, m = j & 7;
    ws[WS_BKV + e] = (j < 8) ? bk[h * 8 + m] : bv[h * 8 + m];
  }
  for (int e = tid; e < 64; e += 256) {          // bq[h][m]
    int m = e & 7, h = e >> 3;
    ws[WS_BQ + e] = (h < 4) ? bq_high[h * 8 + m] : bq_low[(h - 4) * 8 + m];
  }
}

// ---------------- kernel 1: k,v -> per-chunk partial attn/ksum ----------------
// 512 threads = 8 waves, wave w = head w. The 64KB x-tile is staged ONCE per
// block via async global_load_lds (wave w stages rows w, w+8, ...), then all
// 8 heads read it from LDS (ds_read_b128, conflict-free) -- zero VMEM in the
// compute path, single HBM fetch per pixel. Weights via wave-uniform s_loads.
// Row-streaming outer product + DPP reduce. Scalar fmaf (pk was neutral/neg).
__global__ __attribute__((amdgpu_waves_per_eu(1, 8)))
void k1_kv(const float* __restrict__ low,
           const float* __restrict__ ws,
           float* __restrict__ part) {
  const int b = blockIdx.y, chunk = blockIdx.x;
  const int tid = threadIdx.x, lane = tid & 63;
  const int wu = __builtin_amdgcn_readfirstlane(tid >> 6);
  __shared__ float tile[64 * CPX];               // [64 c][256 px] = 64 KB
  const float* lowb = low + (size_t)b * 64 * NPIX + chunk * CPX;
  // ---- stage: 8 rows per wave, each row = 1KB = 64 lanes x 16B ----
#pragma unroll
  for (int i = 0; i < 8; i++) {
    const int row = i * 8 + wu;
    gload_lds16(lowb + (size_t)row * NPIX + lane * 4, &tile[row * CPX]);
  }
  const float* wt = ws + WS_WKVT + wu * 1024;    // wave-uniform -> s_load
  const float* bias = ws + WS_BKV + wu * 16;
  float ka[8][4], va[8][4];
#pragma unroll
  for (int m = 0; m < 8; m++) {
    float bkm = bias[m], bvm = bias[8 + m];
#pragma unroll
    for (int px = 0; px < 4; px++) { ka[m][px] = bkm; va[m][px] = bvm; }
  }
  __syncthreads();                               // drains vmcnt before barrier
  // ---- conv from LDS ----
#pragma unroll 8
  for (int c = 0; c < 64; c++) {
    float4 x = reinterpret_cast<const float4*>(&tile[c * CPX])[lane];
    const float* wr = wt + c * 16;
#pragma unroll
    for (int m = 0; m < 8; m++) {
      float wkm = wr[m], wvm = wr[8 + m];
      ka[m][0] = fmaf(wkm, x.x, ka[m][0]);
      ka[m][1] = fmaf(wkm, x.y, ka[m][1]);
      ka[m][2] = fmaf(wkm, x.z, ka[m][2]);
      ka[m][3] = fmaf(wkm, x.w, ka[m][3]);
      va[m][0] = fmaf(wvm, x.x, va[m][0]);
      va[m][1] = fmaf(wvm, x.y, va[m][1]);
      va[m][2] = fmaf(wvm, x.z, va[m][2]);
      va[m][3] = fmaf(wvm, x.w, va[m][3]);
    }
  }
#pragma unroll
  for (int m = 0; m < 8; m++)
#pragma unroll
    for (int px = 0; px < 4; px++) ka[m][px] = softplus_(ka[m][px]);
  float* pb = part + ((size_t)(b * 8 + wu) * NCH + chunk) * 72;
  // attn rows, streamed: products -> DPP reduce -> lane-63 store, row by row
#pragma unroll
  for (int m = 0; m < 8; m++) {
    float r[8];
#pragma unroll
    for (int c = 0; c < 8; c++) {
      float a = ka[m][0] * va[c][0];
      a = fmaf(ka[m][1], va[c][1], a);
      a = fmaf(ka[m][2], va[c][2], a);
      r[c] = fmaf(ka[m][3], va[c][3], a);
    }
#pragma unroll
    for (int c = 0; c < 8; c++) r[c] = wave_sum63(r[c]);
    if (lane == 63) {
      reinterpret_cast<float4*>(&pb[m * 8])[0] = make_float4(r[0], r[1], r[2], r[3]);
      reinterpret_cast<float4*>(&pb[m * 8])[1] = make_float4(r[4], r[5], r[6], r[7]);
    }
  }
  // ksum row
  {
    float r[8];
#pragma unroll
    for (int m = 0; m < 8; m++)
      r[m] = (ka[m][0] + ka[m][1]) + (ka[m][2] + ka[m][3]);
#pragma unroll
    for (int m = 0; m < 8; m++) r[m] = wave_sum63(r[m]);
    if (lane == 63) {
      reinterpret_cast<float4*>(&pb[64])[0] = make_float4(r[0], r[1], r[2], r[3]);
      reinterpret_cast<float4*>(&pb[64])[1] = make_float4(r[4], r[5], r[6], r[7]);
    }
  }
}

// ---------------- kernel 2: reduce partials, build G and ksumE ----------------
// 64 blocks (b*8+p) x 256 threads; chunk loop split 4-way across sub-waves.
__global__ void k2_g(const float* __restrict__ part, const float* __restrict__ wo,
                     float* __restrict__ ws) {
  const int b = blockIdx.x >> 3, p = blockIdx.x & 7;
  const int tid = threadIdx.x, lane = tid & 63, sub = tid >> 6;
  __shared__ float red[4][72];
  __shared__ float attnL[72];
  const float* src = part + (size_t)(b * 8 + p) * NCH * 72;
  float s0 = 0.0f, s1 = 0.0f;
  for (int ch = sub * (NCH / 4); ch < (sub + 1) * (NCH / 4); ch++) {
    s0 += src[ch * 72 + lane];
    if (lane < 8) s1 += src[ch * 72 + 64 + lane];
  }
  red[sub][lane] = s0;
  if (lane < 8) red[sub][64 + lane] = s1;
  __syncthreads();
  if (tid < 72) attnL[tid] = (red[0][tid] + red[1][tid]) + (red[2][tid] + red[3][tid]);
  __syncthreads();
  if (tid >= 64) {
    if (tid < 72) ws[WS_KSE + (b * 8 + p) * 8 + (tid - 64)] = attnL[tid] + EPSV;
    return;
  }
  const int o = tid;
  float wrow[8];
#pragma unroll
  for (int c = 0; c < 8; c++) wrow[c] = wo[o * 64 + p * 8 + c];
  float* Gp = ws + WS_G + (size_t)(b * 64 + p * 8) * 64;
#pragma unroll
  for (int m = 0; m < 8; m++) {
    float g = 0.0f;
#pragma unroll
    for (int c = 0; c < 8; c++) g = fmaf(attnL[m * 8 + c], wrow[c], g);
    Gp[m * 64 + o] = g;
  }
}

// ---------------- kernel 3: q, norm, fused out-projection ----------------
// 512 threads = 8 waves, lane owns 4 consecutive pixels (float4).
// Phase A: wave w computes qs for head w -> qsL (64 KB). Phase B: wave w
// computes output channels [8w, 8w+8) from all 64 qsL rows (G via s_loads).
__global__ __attribute__((amdgpu_waves_per_eu(1, 8)))
void k3_main(const float* __restrict__ high,
             const float* __restrict__ low,
             const float* __restrict__ ws,
             const float* __restrict__ bo,
             float* __restrict__ out) {
  const int b = blockIdx.y, chunk = blockIdx.x;
  const int tid = threadIdx.x, lane = tid & 63;
  const int wu = __builtin_amdgcn_readfirstlane(tid >> 6);
  __shared__ float qsL[64 * CPX];                // [64 pm][256 px]
  const float* srcb = ((wu < 4) ? high : low) + (size_t)b * 64 * NPIX + chunk * CPX;
  const float* wq  = ws + WS_WQT + wu * 512;
  const float* bq  = ws + WS_BQ + wu * 8;
  const float* kse = ws + WS_KSE + (b * 8 + wu) * 8;
  const float* Gb  = ws + WS_G + (size_t)b * 4096 + wu * 8;
  float qa[8][4];
#pragma unroll
  for (int m = 0; m < 8; m++) {
    float bqm = bq[m];
#pragma unroll
    for (int px = 0; px < 4; px++) qa[m][px] = bqm;
  }
#pragma unroll 8
  for (int c = 0; c < 64; c++) {
    float4 x = reinterpret_cast<const float4*>(srcb + (size_t)c * NPIX)[lane];
    const float* wr = wq + c * 8;
#pragma unroll
    for (int m = 0; m < 8; m++) {
      float w = wr[m];
      qa[m][0] = fmaf(w, x.x, qa[m][0]);
      qa[m][1] = fmaf(w, x.y, qa[m][1]);
      qa[m][2] = fmaf(w, x.z, qa[m][2]);
      qa[m][3] = fmaf(w, x.w, qa[m][3]);
    }
  }
  float s[4] = {0.0f, 0.0f, 0.0f, 0.0f};
#pragma unroll
  for (int m = 0; m < 8; m++) {
    float km = kse[m];
#pragma unroll
    for (int px = 0; px < 4; px++) {
      qa[m][px] = softplus_(qa[m][px]);
      s[px] = fmaf(qa[m][px], km, s[px]);
    }
  }
  float r0 = 1.0f / s[0], r1 = 1.0f / s[1], r2 = 1.0f / s[2], r3 = 1.0f / s[3];
#pragma unroll
  for (int m = 0; m < 8; m++) {
    reinterpret_cast<float4*>(&qsL[(wu * 8 + m) * CPX])[lane] =
        make_float4(qa[m][0] * r0, qa[m][1] * r1, qa[m][2] * r2, qa[m][3] * r3);
  }
  __syncthreads();
  float acc[8][4];
#pragma unroll
  for (int j = 0; j < 8; j++) {
    float bj = bo[wu * 8 + j];
#pragma unroll
    for (int px = 0; px < 4; px++) acc[j][px] = bj;
  }
#pragma unroll 4
  for (int pm = 0; pm < 64; pm++) {
    float4 qv = reinterpret_cast<const float4*>(&qsL[pm * CPX])[lane];
    const float* gr = Gb + pm * 64;              // wave-uniform -> s_load
#pragma unroll
    for (int j = 0; j < 8; j++) {
      float g = gr[j];
      acc[j][0] = fmaf(g, qv.x, acc[j][0]);
      acc[j][1] = fmaf(g, qv.y, acc[j][1]);
      acc[j][2] = fmaf(g, qv.z, acc[j][2]);
      acc[j][3] = fmaf(g, qv.w, acc[j][3]);
    }
  }
  float* ob = out + (size_t)(b * 64 + wu * 8) * NPIX + chunk * CPX;
#pragma unroll
  for (int j = 0; j < 8; j++) {
    reinterpret_cast<float4*>(ob + (size_t)j * NPIX)[lane] =
        make_float4(acc[j][0], acc[j][1], acc[j][2], acc[j][3]);
  }
}

extern "C" void kernel_launch(void* const* d_in, const int* in_sizes, int n_in,
                              void* d_out, int out_size, void* d_ws, size_t ws_size,
                              hipStream_t stream) {
  const float* high    = (const float*)d_in[0];
  const float* low     = (const float*)d_in[1];
  const float* wq_high = (const float*)d_in[2];
  const float* bq_high = (const float*)d_in[3];
  const float* wq_low  = (const float*)d_in[4];
  const float* bq_low  = (const float*)d_in[5];
  const float* wk      = (const float*)d_in[6];
  const float* bk      = (const float*)d_in[7];
  const float* wv      = (const float*)d_in[8];
  const float* bv      = (const float*)d_in[9];
  const float* wo      = (const float*)d_in[10];
  const float* bo      = (const float*)d_in[11];
  float* ws  = (float*)d_ws;
  float* out = (float*)d_out;

  k0_pack<<<1, 256, 0, stream>>>(wq_high, bq_high, wq_low, bq_low, wk, bk, wv, bv, ws);
  dim3 grid(NCH, NB);
  k1_kv<<<grid, 512, 0, stream>>>(low, ws, ws + WS_PART);
  k2_g<<<64, 256, 0, stream>>>(ws + WS_PART, wo, ws);
  k3_main<<<grid, 512, 0, stream>>>(high, low, ws, bo, out);
}

// Round 12
// 130.982 us; speedup vs baseline: 1.0932x; 1.0932x over previous
//
#include <hip/hip_runtime.h>

// MCA linear attention, fp32. B=8, C=64, H=W=160, P=8 heads, d=8, N=25600.
#define NPIX  25600
#define NB    8
#define NCH   100    // k1 pixel chunks per batch (256 px each)
#define CPX   256    // k1 chunk pixels (64 lanes x 4 px)
#define KCH   200    // k3 pixel chunks per batch (128 px each)
#define KPX   128    // k3 chunk pixels (64 lanes x 2 px)
#define EPSV  1e-6f

// workspace layout (float offsets)
#define WS_WKVT  0        // [8 h][64 c][16]  (8 wk rows, 8 wv rows, transposed)
#define WS_WQT   8192     // [8 h][64 c][8]
#define WS_BKV   12288    // [8 h][16]
#define WS_BQ    12416    // [8 h][8]
#define WS_PART  12480    // [64 bh][100 ch][72]  (contiguous 72 per chunk)
#define WS_G     473280   // [8 b][64 pm][64 o]
#define WS_KSE   506048   // [8 b][8 p][8 m]

__device__ __forceinline__ float softplus_(float x) {
  // hw v_exp/v_log path; for x>20, log(1+e^x)==x to fp32 precision
  return (x > 20.0f) ? x : __logf(1.0f + __expf(x));
}

// DPP wave64 sum: row_shr 1/2/4/8 then row_bcast:15 (rows 1,3) and
// row_bcast:31 (rows 2,3). Full sum lands in lane 63. old=0 makes masked /
// invalid lanes contribute 0 regardless of bound_ctrl interpretation.
template <int CTRL, int RMASK>
__device__ __forceinline__ float dpp_add(float x) {
  int y = __builtin_amdgcn_update_dpp(0, __float_as_int(x), CTRL, RMASK, 0xf, false);
  return x + __int_as_float(y);
}
__device__ __forceinline__ float wave_sum63(float x) {
  x = dpp_add<0x111, 0xf>(x);   // row_shr:1
  x = dpp_add<0x112, 0xf>(x);   // row_shr:2
  x = dpp_add<0x114, 0xf>(x);   // row_shr:4
  x = dpp_add<0x118, 0xf>(x);   // row_shr:8
  x = dpp_add<0x142, 0xa>(x);   // row_bcast:15 -> rows 1,3
  x = dpp_add<0x143, 0xc>(x);   // row_bcast:31 -> rows 2,3
  return x;                     // lane 63 holds the wave total
}

// ---------------- kernel 0: pack weights/biases transposed ----------------
__global__ void k0_pack(const float* __restrict__ wq_high, const float* __restrict__ bq_high,
                        const float* __restrict__ wq_low,  const float* __restrict__ bq_low,
                        const float* __restrict__ wk, const float* __restrict__ bk,
                        const float* __restrict__ wv, const float* __restrict__ bv,
                        float* __restrict__ ws) {
  const int tid = threadIdx.x;
  for (int e = tid; e < 8192; e += 256) {        // wkvT[h][c][j]
    int j = e & 15, c = (e >> 4) & 63, h = e >> 10, m = j & 7;
    float v = (j < 8) ? wk[(h * 8 + m) * 64 + c] : wv[(h * 8 + m) * 64 + c];
    ws[WS_WKVT + e] = v;
  }
  for (int e = tid; e < 4096; e += 256) {        // wqT[h][c][m]
    int m = e & 7, c = (e >> 3) & 63, h = e >> 9;
    float v = (h < 4) ? wq_high[(h * 8 + m) * 64 + c]
                      : wq_low[((h - 4) * 8 + m) * 64 + c];
    ws[WS_WQT + e] = v;
  }
  for (int e = tid; e < 128; e += 256) {         // bkv[h][j]
    int j = e & 15, h = e >> 4, m = j & 7;
    ws[WS_BKV + e] = (j < 8) ? bk[h * 8 + m] : bv[h * 8 + m];
  }
  for (int e = tid; e < 64; e += 256) {          // bq[h][m]
    int m = e & 7, h = e >> 3;
    ws[WS_BQ + e] = (h < 4) ? bq_high[h * 8 + m] : bq_low[(h - 4) * 8 + m];
  }
}

// ---------------- kernel 1: k,v -> per-chunk partial attn/ksum ----------------
// R9's measured-best structure: 256 threads = 4 waves; block (chunk, b, half)
// -> wave w = head half*4+w. 4 heads/block keeps the scalar-L1 weight
// footprint at 16KB (8-wave blocks thrash it). Lane owns 4 px (float4 loads).
// Weights via wave-uniform s_loads; row-streaming + DPP reduce; scalar fmaf.
__global__ __attribute__((amdgpu_waves_per_eu(1, 8)))
void k1_kv(const float* __restrict__ low,
           const float* __restrict__ ws,
           float* __restrict__ part) {
  const int b = blockIdx.y >> 1, half = blockIdx.y & 1, chunk = blockIdx.x;
  const int tid = threadIdx.x, lane = tid & 63;
  const int wu = __builtin_amdgcn_readfirstlane(half * 4 + (tid >> 6));
  const float* lowb = low + (size_t)b * 64 * NPIX + chunk * CPX;
  const float* wt = ws + WS_WKVT + wu * 1024;    // wave-uniform -> s_load
  const float* bias = ws + WS_BKV + wu * 16;
  float ka[8][4], va[8][4];
#pragma unroll
  for (int m = 0; m < 8; m++) {
    float bkm = bias[m], bvm = bias[8 + m];
#pragma unroll
    for (int px = 0; px < 4; px++) { ka[m][px] = bkm; va[m][px] = bvm; }
  }
#pragma unroll 8
  for (int c = 0; c < 64; c++) {
    float4 x = reinterpret_cast<const float4*>(lowb + (size_t)c * NPIX)[lane];
    const float* wr = wt + c * 16;
#pragma unroll
    for (int m = 0; m < 8; m++) {
      float wkm = wr[m], wvm = wr[8 + m];
      ka[m][0] = fmaf(wkm, x.x, ka[m][0]);
      ka[m][1] = fmaf(wkm, x.y, ka[m][1]);
      ka[m][2] = fmaf(wkm, x.z, ka[m][2]);
      ka[m][3] = fmaf(wkm, x.w, ka[m][3]);
      va[m][0] = fmaf(wvm, x.x, va[m][0]);
      va[m][1] = fmaf(wvm, x.y, va[m][1]);
      va[m][2] = fmaf(wvm, x.z, va[m][2]);
      va[m][3] = fmaf(wvm, x.w, va[m][3]);
    }
  }
#pragma unroll
  for (int m = 0; m < 8; m++)
#pragma unroll
    for (int px = 0; px < 4; px++) ka[m][px] = softplus_(ka[m][px]);
  float* pb = part + ((size_t)(b * 8 + wu) * NCH + chunk) * 72;
  // attn rows, streamed: products -> DPP reduce -> lane-63 store, row by row
#pragma unroll
  for (int m = 0; m < 8; m++) {
    float r[8];
#pragma unroll
    for (int c = 0; c < 8; c++) {
      float a = ka[m][0] * va[c][0];
      a = fmaf(ka[m][1], va[c][1], a);
      a = fmaf(ka[m][2], va[c][2], a);
      r[c] = fmaf(ka[m][3], va[c][3], a);
    }
#pragma unroll
    for (int c = 0; c < 8; c++) r[c] = wave_sum63(r[c]);
    if (lane == 63) {
      reinterpret_cast<float4*>(&pb[m * 8])[0] = make_float4(r[0], r[1], r[2], r[3]);
      reinterpret_cast<float4*>(&pb[m * 8])[1] = make_float4(r[4], r[5], r[6], r[7]);
    }
  }
  // ksum row
  {
    float r[8];
#pragma unroll
    for (int m = 0; m < 8; m++)
      r[m] = (ka[m][0] + ka[m][1]) + (ka[m][2] + ka[m][3]);
#pragma unroll
    for (int m = 0; m < 8; m++) r[m] = wave_sum63(r[m]);
    if (lane == 63) {
      reinterpret_cast<float4*>(&pb[64])[0] = make_float4(r[0], r[1], r[2], r[3]);
      reinterpret_cast<float4*>(&pb[64])[1] = make_float4(r[4], r[5], r[6], r[7]);
    }
  }
}

// ---------------- kernel 2: reduce partials, build G and ksumE ----------------
// 64 blocks (b*8+p) x 256 threads; chunk loop split 4-way across sub-waves.
__global__ void k2_g(const float* __restrict__ part, const float* __restrict__ wo,
                     float* __restrict__ ws) {
  const int b = blockIdx.x >> 3, p = blockIdx.x & 7;
  const int tid = threadIdx.x, lane = tid & 63, sub = tid >> 6;
  __shared__ float red[4][72];
  __shared__ float attnL[72];
  const float* src = part + (size_t)(b * 8 + p) * NCH * 72;
  float s0 = 0.0f, s1 = 0.0f;
  for (int ch = sub * (NCH / 4); ch < (sub + 1) * (NCH / 4); ch++) {
    s0 += src[ch * 72 + lane];
    if (lane < 8) s1 += src[ch * 72 + 64 + lane];
  }
  red[sub][lane] = s0;
  if (lane < 8) red[sub][64 + lane] = s1;
  __syncthreads();
  if (tid < 72) attnL[tid] = (red[0][tid] + red[1][tid]) + (red[2][tid] + red[3][tid]);
  __syncthreads();
  if (tid >= 64) {
    if (tid < 72) ws[WS_KSE + (b * 8 + p) * 8 + (tid - 64)] = attnL[tid] + EPSV;
    return;
  }
  const int o = tid;
  float wrow[8];
#pragma unroll
  for (int c = 0; c < 8; c++) wrow[c] = wo[o * 64 + p * 8 + c];
  float* Gp = ws + WS_G + (size_t)(b * 64 + p * 8) * 64;
#pragma unroll
  for (int m = 0; m < 8; m++) {
    float g = 0.0f;
#pragma unroll
    for (int c = 0; c < 8; c++) g = fmaf(attnL[m * 8 + c], wrow[c], g);
    Gp[m * 64 + o] = g;
  }
}

// ---------------- kernel 3: q, norm, fused out-projection ----------------
// 512 threads = 8 waves, lane owns 2 px (float2). qsL = 32KB -> 4 blocks/CU
// (LDS 128KB, 2048 thr: both CU limits exactly) = 2x the wave residency of
// the 64KB variant; grid 1600 quarters the tail quantum. Phase A: wave w ->
// qs for head w. Phase B: wave w -> channels [8w,8w+8) (G via s_loads).
__global__ __attribute__((amdgpu_waves_per_eu(1, 8)))
void k3_main(const float* __restrict__ high,
             const float* __restrict__ low,
             const float* __restrict__ ws,
             const float* __restrict__ bo,
             float* __restrict__ out) {
  const int b = blockIdx.y, chunk = blockIdx.x;
  const int tid = threadIdx.x, lane = tid & 63;
  const int wu = __builtin_amdgcn_readfirstlane(tid >> 6);
  __shared__ float qsL[64 * KPX];                // [64 pm][128 px] = 32 KB
  const float* srcb = ((wu < 4) ? high : low) + (size_t)b * 64 * NPIX + chunk * KPX;
  const float* wq  = ws + WS_WQT + wu * 512;
  const float* bq  = ws + WS_BQ + wu * 8;
  const float* kse = ws + WS_KSE + (b * 8 + wu) * 8;
  const float* Gb  = ws + WS_G + (size_t)b * 4096 + wu * 8;
  float qa[8][2];
#pragma unroll
  for (int m = 0; m < 8; m++) { qa[m][0] = bq[m]; qa[m][1] = bq[m]; }
#pragma unroll 8
  for (int c = 0; c < 64; c++) {
    float2 x = reinterpret_cast<const float2*>(srcb + (size_t)c * NPIX)[lane];
    const float* wr = wq + c * 8;
#pragma unroll
    for (int m = 0; m < 8; m++) {
      float w = wr[m];
      qa[m][0] = fmaf(w, x.x, qa[m][0]);
      qa[m][1] = fmaf(w, x.y, qa[m][1]);
    }
  }
  float s0 = 0.0f, s1 = 0.0f;
#pragma unroll
  for (int m = 0; m < 8; m++) {
    float km = kse[m];
    qa[m][0] = softplus_(qa[m][0]);
    qa[m][1] = softplus_(qa[m][1]);
    s0 = fmaf(qa[m][0], km, s0);
    s1 = fmaf(qa[m][1], km, s1);
  }
  const float r0 = 1.0f / s0, r1 = 1.0f / s1;
#pragma unroll
  for (int m = 0; m < 8; m++) {
    reinterpret_cast<float2*>(&qsL[(wu * 8 + m) * KPX])[lane] =
        make_float2(qa[m][0] * r0, qa[m][1] * r1);
  }
  __syncthreads();
  float acc[8][2];
#pragma unroll
  for (int j = 0; j < 8; j++) { acc[j][0] = bo[wu * 8 + j]; acc[j][1] = acc[j][0]; }
#pragma unroll 8
  for (int pm = 0; pm < 64; pm++) {
    float2 qv = reinterpret_cast<const float2*>(&qsL[pm * KPX])[lane];
    const float* gr = Gb + pm * 64;              // wave-uniform -> s_load
#pragma unroll
    for (int j = 0; j < 8; j++) {
      float g = gr[j];
      acc[j][0] = fmaf(g, qv.x, acc[j][0]);
      acc[j][1] = fmaf(g, qv.y, acc[j][1]);
    }
  }
  float* ob = out + (size_t)(b * 64 + wu * 8) * NPIX + chunk * KPX;
#pragma unroll
  for (int j = 0; j < 8; j++) {
    reinterpret_cast<float2*>(ob + (size_t)j * NPIX)[lane] =
        make_float2(acc[j][0], acc[j][1]);
  }
}

extern "C" void kernel_launch(void* const* d_in, const int* in_sizes, int n_in,
                              void* d_out, int out_size, void* d_ws, size_t ws_size,
                              hipStream_t stream) {
  const float* high    = (const float*)d_in[0];
  const float* low     = (const float*)d_in[1];
  const float* wq_high = (const float*)d_in[2];
  const float* bq_high = (const float*)d_in[3];
  const float* wq_low  = (const float*)d_in[4];
  const float* bq_low  = (const float*)d_in[5];
  const float* wk      = (const float*)d_in[6];
  const float* bk      = (const float*)d_in[7];
  const float* wv      = (const float*)d_in[8];
  const float* bv      = (const float*)d_in[9];
  const float* wo      = (const float*)d_in[10];
  const float* bo      = (const float*)d_in[11];
  float* ws  = (float*)d_ws;
  float* out = (float*)d_out;

  k0_pack<<<1, 256, 0, stream>>>(wq_high, bq_high, wq_low, bq_low, wk, bk, wv, bv, ws);
  dim3 grid1(NCH, NB * 2);
  k1_kv<<<grid1, 256, 0, stream>>>(low, ws, ws + WS_PART);
  k2_g<<<64, 256, 0, stream>>>(ws + WS_PART, wo, ws);
  dim3 grid3(KCH, NB);
  k3_main<<<grid3, 512, 0, stream>>>(high, low, ws, bo, out);
}